// Round 5
// baseline (5932.677 us; speedup 1.0000x reference)
//
#include <hip/hip_runtime.h>

// Two-phase persistent LSTM for MI355X.  B=32, T=1024, D_IN=512, H=512.
//
// R9 = R8 with a cheap-retry poll in lstm_recur.
//   R8 evidence: recur = 3.97 us/step; VALU accounting gives ~4-5 poll
//   attempts/step, each re-issuing ALL 64 agent-scope loads + vmcnt(0)
//   drain (~1500 cy) because one late producer invalidates the whole
//   attempt.  Records are MONOTONIC within an epoch (immutable until the
//   E+2 overwrite, which the R4 throttle orders after this poll), so
//   validated slots never need re-loading.  New poll: first pass loads all
//   64; validity tracked per kk-group (wave-uniform bitmask via __all ->
//   scalar branches, zero divergence); retries reload ONLY missing kk
//   groups (4 loads each).  Protocol/record format/epochs: R4-identical.
//
// Structure (unchanged from R8):
//   pregate(chunk): 256 WGs x 512 thr (8 waves REQUIRED: (mt,gsel) =
//     (wave&1, wave>>1) covers 2 batch halves x 4 gates).
//     preg[lt][gate][hcol][b] = x_t @ W_g + b_g (f32, MFMA C-layout).
//   recur(chunk): 64 WGs x 256 thr, self-validating 8B h-records
//     {epoch(hi32)|2xf16(lo32)}, polling load IS the data load (R5 proved
//     sentinel indirection regresses).  Global epochs, monotone across
//     chunks; c_state persists in ws.
//   Chunked over T to fit any ws_size; falls back to R4 if ws < 4.4 MB.

#define T_STEPS 1024
#define BATCH   32
#define DIN     512
#define H       512
#define NWG     64
#define HC      8
#define XSTRIDE 520        // f16 elems; 1040B row = bank offset 4 -> 2-way max (free)
#define GSTRIDE 34         // padded f32 row stride of LDS gate tile
#define RECS_PER_PARITY 8192   // 16 kk * 512   (R4 record format)

typedef _Float16 half8  __attribute__((ext_vector_type(8)));
typedef _Float16 half4v __attribute__((ext_vector_type(4)));
typedef float    f32x4  __attribute__((ext_vector_type(4)));
typedef unsigned long long u64;
typedef unsigned int       u32;

#define AT_LD_U64(p)   __hip_atomic_load((const u64*)(p), __ATOMIC_RELAXED, __HIP_MEMORY_SCOPE_AGENT)
#define AT_ST_U64(p,v) __hip_atomic_store((u64*)(p), (v), __ATOMIC_RELAXED, __HIP_MEMORY_SCOPE_AGENT)

__device__ __forceinline__ float sigmoidf_(float x) {
    return 1.0f / (1.0f + __expf(-x));
}
__device__ __forceinline__ float tanhf_(float x) {
    return 1.0f - 2.0f / (1.0f + __expf(2.0f * x));
}

// ======================= kernel 1: pre-gate GEMM ========================
// Grid: 256 WGs x 512 threads = 32 col-blocks (cb: 16 h-cols) x 8 t-ranges.
// Waves (8): mt = wave&1 (batch half), gsel = wave>>1 (gate 0..3) — one
// gate per wave.  Output preg[lt][gate][hcol][b], b fastest, bias folded,
// exactly MFMA C-layout so recur seeds its accumulator with one dwordx4.
__global__ __launch_bounds__(512, 1) void lstm_pregate(
    const float* __restrict__ x,
    const float* __restrict__ Wi, const float* __restrict__ Wf,
    const float* __restrict__ Wc, const float* __restrict__ Wo,
    const float* __restrict__ bi, const float* __restrict__ bf,
    const float* __restrict__ bc, const float* __restrict__ bo,
    float* __restrict__ preg, int t0, int tc)
{
    __shared__ _Float16 xbuf[2 * BATCH * XSTRIDE];   // ~65 KB, double-buffered

    const int tid  = threadIdx.x;
    const int wg   = blockIdx.x;
    const int cb   = wg & 31;          // h-cols [cb*16, cb*16+16)
    const int tq   = wg >> 5;          // t-range within chunk
    const int tcq  = tc >> 3;          // steps per t-range (>= 2)
    const int tb   = t0 + tq * tcq;    // global first step of this WG
    const int lane = tid & 63;
    const int wave = tid >> 6;         // 0..7
    const int mt   = wave & 1;         // batch half
    const int gsel = wave >> 1;        // gate 0..3  (8 waves REQUIRED)
    const int n_local = lane & 15;
    const int kq   = lane >> 4;
    const int row  = mt * 16 + n_local;    // batch row for A-frag
    const int hcol = cb * 16 + n_local;

    const float* Wmat = (gsel == 0) ? Wi : (gsel == 1) ? Wf : (gsel == 2) ? Wc : Wo;
    const float* bvec = (gsel == 0) ? bi : (gsel == 1) ? bf : (gsel == 2) ? bc : bo;
    const float bv = bvec[hcol];

    // ---- one-time: W B-fragments into VGPRs (one gate, 16 kk) ----------
    half8 bfrag[16];
    #pragma unroll
    for (int kk = 0; kk < 16; ++kk) {
        #pragma unroll
        for (int jj = 0; jj < 8; ++jj) {
            int k = kk * 32 + kq * 8 + jj;
            bfrag[kk][jj] = (_Float16)Wmat[k * H + hcol];
        }
    }

    // ---- x staging (f32 -> f16), 512-thread version --------------------
    // 32 rows x 16 threads/row; each thread 8 float4 loads (stride 64 cols).
    auto stage = [&](int t, int buf) {
        const int sb = tid >> 4;            // batch row 0..31
        const int so = (tid & 15) * 4;
        const float* xr = x + ((size_t)sb * T_STEPS + t) * DIN;
        _Float16* xb = &xbuf[buf * (BATCH * XSTRIDE)];
        #pragma unroll
        for (int q = 0; q < 8; ++q) {
            int colq = so + q * 64;
            float4 v = *(const float4*)(xr + colq);
            half4v hv = { (_Float16)v.x, (_Float16)v.y,
                          (_Float16)v.z, (_Float16)v.w };
            *(half4v*)&xb[sb * XSTRIDE + colq] = hv;
        }
    };

    stage(tb, 0);
    stage(tb + 1, 1);
    __syncthreads();

    for (int lt = 0; lt < tcq; ++lt) {
        f32x4 a0 = {0.f, 0.f, 0.f, 0.f};
        f32x4 a1 = {0.f, 0.f, 0.f, 0.f};
        const _Float16* xr2 =
            &xbuf[(lt & 1) * (BATCH * XSTRIDE) + row * XSTRIDE + kq * 8];
        #pragma unroll
        for (int kk = 0; kk < 16; kk += 2) {
            half8 v0 = *(const half8*)(xr2 + kk * 32);
            half8 v1 = *(const half8*)(xr2 + (kk + 1) * 32);
            a0 = __builtin_amdgcn_mfma_f32_16x16x32_f16(v0, bfrag[kk],     a0, 0, 0, 0);
            a1 = __builtin_amdgcn_mfma_f32_16x16x32_f16(v1, bfrag[kk + 1], a1, 0, 0, 0);
        }
        f32x4 aw;
        #pragma unroll
        for (int r = 0; r < 4; ++r) aw[r] = a0[r] + a1[r] + bv;

        // C/D layout: col = n_local (-> hcol), row = kq*4 + r (-> batch
        // within half mt).  Chunk-local step index.
        const size_t base =
            (((size_t)(tb - t0 + lt) * 4 + gsel) * 512 + hcol) * 32
            + mt * 16 + kq * 4;
        *(f32x4*)&preg[base] = aw;

        __syncthreads();
        if (lt + 2 < tcq) stage(tb + lt + 2, lt & 1);
    }
}

// ======================= kernel 2: recurrence ===========================
__global__ __launch_bounds__(256, 1) void lstm_recur(
    const float* __restrict__ init_states,
    const float* __restrict__ Ui, const float* __restrict__ Uf,
    const float* __restrict__ Uc, const float* __restrict__ Uo,
    const float* __restrict__ preg,   // [tc][4][512][32] f32, bias folded
    float* __restrict__ out,
    u64* __restrict__ hrec,           // 2 parities x 8192 records
    float* __restrict__ cst,          // [32][512] persistent c-state
    int t0, int tc)
{
    __shared__ float gbuf[2 * BATCH * GSTRIDE];

    const int tid  = threadIdx.x;
    const int wg   = blockIdx.x;
    const int lane = tid & 63;
    const int wave = tid >> 6;
    const int mt   = wave & 1;
    const int nt   = wave >> 1;
    const int row  = mt * 16 + (lane & 15);
    const int kq   = lane >> 4;

    const int eb   = tid >> 3;
    const int ej   = tid & 7;
    const int ecol = wg * HC + ej;

    // c-state: from init on chunk 0, else from ws
    float c_state = (t0 == 0) ? init_states[BATCH * H + eb * H + ecol]
                              : cst[eb * H + ecol];

    // publish h0 (epoch 1, parity 0) only on chunk 0; later chunks rely on
    // the previous launch's final publish (global epochs are monotone).
    if (t0 == 0) {
        _Float16 h0 = (_Float16)init_states[eb * H + ecol];
        u32 hu  = (u32)__builtin_bit_cast(unsigned short, h0);
        u32 oth = __shfl_down(hu, 1);
        if ((tid & 1) == 0) {
            const int ridx = (wg >> 2) * 512 + (ej >> 1) * 128 + eb * 4 + (wg & 3);
            AT_ST_U64(&hrec[ridx], ((u64)1u << 32) | (u64)(hu | (oth << 16)));
        }
    }

    // ---- one-time: U B-fragments into VGPRs ----------------------------
    const int n_local = lane & 15;
    const int gi   = nt * 2 + (n_local >> 3);      // gate 0..3 (nt in 0..1)
    const int wcol = wg * HC + (n_local & 7);
    const float* Umat = (gi == 0) ? Ui : (gi == 1) ? Uf : (gi == 2) ? Uc : Uo;

    half8 bfrag[16];                    // 64 VGPRs/lane, persistent
    #pragma unroll
    for (int kk = 0; kk < 16; ++kk) {
        #pragma unroll
        for (int jj = 0; jj < 8; ++jj) {
            int k = kk * 32 + kq * 8 + jj;
            bfrag[kk][jj] = (_Float16)Umat[k * H + wcol];
        }
    }

    // pre-gate in MFMA C-layout: one dwordx4/lane/step, prefetched 1 ahead
    const size_t pgbase =
        ((size_t)gi * 512 + wcol) * 32 + mt * 16 + kq * 4;
    f32x4 pg = *(const f32x4*)&preg[pgbase];           // lt = 0

    const int ridx_base = row * 4 + kq;
    const int widx = (wg >> 2) * 512 + (ej >> 1) * 128 + eb * 4 + (wg & 3);

    for (int lt = 0; lt < tc; ++lt) {
        const int gt = t0 + lt;                        // global step
        const u64* rb = hrec + (size_t)(gt & 1) * RECS_PER_PARITY;
        const u32 target = (u32)(gt + 1);

        // ---- cheap-retry poll ------------------------------------------
        // Records are monotonic within an epoch: once slot (kk,*) matches
        // `target` it stays valid until the E+2 overwrite, which the
        // throttle orders after this poll completes.  So validated kk
        // groups are never re-loaded; retries touch only missing groups.
        // kkvalid is wave-uniform (__all) -> scalar branches, no
        // divergence.
        u64 rec[64];
        #pragma unroll
        for (int kk = 0; kk < 16; ++kk) {
            #pragma unroll
            for (int s = 0; s < 4; ++s)
                rec[kk * 4 + s] = AT_LD_U64(&rb[kk * 512 + s * 128 + ridx_base]);
        }
        u32 kkvalid = 0;
        unsigned spins = 0;
        for (;;) {
            #pragma unroll
            for (int kk = 0; kk < 16; ++kk) {
                if (!(kkvalid & (1u << kk))) {
                    int ok = ((u32)(rec[kk * 4 + 0] >> 32) == target)
                           & ((u32)(rec[kk * 4 + 1] >> 32) == target)
                           & ((u32)(rec[kk * 4 + 2] >> 32) == target)
                           & ((u32)(rec[kk * 4 + 3] >> 32) == target);
                    if (__all(ok)) kkvalid |= (1u << kk);
                }
            }
            if (kkvalid == 0xFFFFu) break;
            if (++spins > 1000000u) break;   // safety valve
            #pragma unroll
            for (int kk = 0; kk < 16; ++kk) {
                if (!(kkvalid & (1u << kk))) {
                    #pragma unroll
                    for (int s = 0; s < 4; ++s)
                        rec[kk * 4 + s] =
                            AT_LD_U64(&rb[kk * 512 + s * 128 + ridx_base]);
                }
            }
        }

        // prefetch next step's pre-gate (consumed after next poll)
        f32x4 pgn = pg;
        if (lt + 1 < tc)
            pgn = *(const f32x4*)&preg[(size_t)(lt + 1) * 65536 + pgbase];

        // h-half matmul from registers; acc starts at pre-gate (x@W + b)
        float* gb = &gbuf[(gt & 1) * (BATCH * GSTRIDE)];
        {
            f32x4 acc  = pg;
            f32x4 acc2 = {0.f, 0.f, 0.f, 0.f};
            #pragma unroll
            for (int kk = 0; kk < 16; kk += 2) {
                union { u32 d[4]; half8 h; } a0, a1;
                #pragma unroll
                for (int s = 0; s < 4; ++s) {
                    a0.d[s] = (u32)rec[kk * 4 + s];
                    a1.d[s] = (u32)rec[(kk + 1) * 4 + s];
                }
                acc  = __builtin_amdgcn_mfma_f32_16x16x32_f16(a0.h, bfrag[kk],     acc,  0, 0, 0);
                acc2 = __builtin_amdgcn_mfma_f32_16x16x32_f16(a1.h, bfrag[kk + 1], acc2, 0, 0, 0);
            }
            #pragma unroll
            for (int r = 0; r < 4; ++r) {
                gb[(mt * 16 + kq * 4 + r) * GSTRIDE + nt * 16 + n_local] =
                    acc[r] + acc2[r];
            }
        }
        __syncthreads();   // the ONLY barrier per step

        float h_val;
        {
            float pi  = gb[eb * GSTRIDE + ej];
            float pf  = gb[eb * GSTRIDE + 8 + ej];
            float pgg = gb[eb * GSTRIDE + 16 + ej];
            float po  = gb[eb * GSTRIDE + 24 + ej];
            float ig = sigmoidf_(pi);
            float fg = sigmoidf_(pf);
            float gg = tanhf_(pgg);
            float og = sigmoidf_(po);
            c_state  = fg * c_state + ig * gg;
            h_val    = og * tanhf_(c_state);

            if (gt + 1 < T_STEPS) {
                _Float16 hh = (_Float16)h_val;
                u32 hu  = (u32)__builtin_bit_cast(unsigned short, hh);
                u32 oth = __shfl_down(hu, 1);
                if ((tid & 1) == 0) {
                    AT_ST_U64(&hrec[(size_t)((gt + 1) & 1) * RECS_PER_PARITY + widx],
                              ((u64)(u32)(gt + 2) << 32) | (u64)(hu | (oth << 16)));
                }
            }
        }

        out[((size_t)eb * T_STEPS + gt) * H + ecol] = h_val;
        pg = pgn;
    }

    // persist c-state for the next chunk launch
    cst[eb * H + ecol] = c_state;
}

// ======================= fallback: R4 single kernel =====================
__global__ __launch_bounds__(256, 1) void lstm_persistent_fb(
    const float* __restrict__ x,
    const float* __restrict__ init_states,
    const float* __restrict__ Wi, const float* __restrict__ Ui, const float* __restrict__ bi,
    const float* __restrict__ Wf, const float* __restrict__ Uf, const float* __restrict__ bf,
    const float* __restrict__ Wc, const float* __restrict__ Uc, const float* __restrict__ bc,
    const float* __restrict__ Wo, const float* __restrict__ Uo, const float* __restrict__ bo,
    float* __restrict__ out,
    u64* __restrict__ hrec)
{
    __shared__ _Float16 xbuf[2 * BATCH * XSTRIDE];
    __shared__ float    gbuf[2 * BATCH * GSTRIDE];

    const int tid  = threadIdx.x;
    const int wg   = blockIdx.x;
    const int lane = tid & 63;
    const int wave = tid >> 6;
    const int mt   = wave & 1;
    const int nt   = wave >> 1;
    const int row  = mt * 16 + (lane & 15);
    const int kq   = lane >> 4;

    const int eb   = tid >> 3;
    const int ej   = tid & 7;
    const int ecol = wg * HC + ej;

    float c_state = init_states[BATCH * H + eb * H + ecol];
    {
        _Float16 h0 = (_Float16)init_states[eb * H + ecol];
        u32 hu  = (u32)__builtin_bit_cast(unsigned short, h0);
        u32 oth = __shfl_down(hu, 1);
        if ((tid & 1) == 0) {
            const int ridx = (wg >> 2) * 512 + (ej >> 1) * 128 + eb * 4 + (wg & 3);
            AT_ST_U64(&hrec[ridx], ((u64)1u << 32) | (u64)(hu | (oth << 16)));
        }
    }

    const int n_local = lane & 15;
    const int gi   = nt * 2 + (n_local >> 3);
    const int wcol = wg * HC + (n_local & 7);
    const float* Wmat = (gi == 0) ? Wi : (gi == 1) ? Wf : (gi == 2) ? Wc : Wo;
    const float* Umat = (gi == 0) ? Ui : (gi == 1) ? Uf : (gi == 2) ? Uc : Uo;

    half8 bfrag[32];
    #pragma unroll
    for (int kk = 0; kk < 16; ++kk) {
        #pragma unroll
        for (int jj = 0; jj < 8; ++jj) {
            int k = kk * 32 + kq * 8 + jj;
            bfrag[kk][jj]      = (_Float16)Wmat[k * H + wcol];
            bfrag[16 + kk][jj] = (_Float16)Umat[k * H + wcol];
        }
    }

    const float bi_v = bi[ecol], bf_v = bf[ecol], bc_v = bc[ecol], bo_v = bo[ecol];

    auto stage = [&](int t, int buf) {
        const int sb = tid >> 3;
        const int so = (tid & 7) * 4;
        const float* xr = x + ((size_t)sb * T_STEPS + t) * DIN;
        _Float16* xb = &xbuf[buf * (BATCH * XSTRIDE)];
        #pragma unroll
        for (int q = 0; q < 16; ++q) {
            int colq = so + q * 32;
            float4 v = *(const float4*)(xr + colq);
            half4v hv = { (_Float16)v.x, (_Float16)v.y,
                          (_Float16)v.z, (_Float16)v.w };
            *(half4v*)&xb[sb * XSTRIDE + colq] = hv;
        }
    };
    auto xmm = [&](int buf) -> f32x4 {
        f32x4 ax  = {0.f, 0.f, 0.f, 0.f};
        f32x4 ax2 = {0.f, 0.f, 0.f, 0.f};
        const _Float16* xr2 = &xbuf[buf * (BATCH * XSTRIDE) + row * XSTRIDE + kq * 8];
        #pragma unroll
        for (int kk = 0; kk < 16; kk += 2) {
            half8 a0 = *(const half8*)(xr2 + kk * 32);
            half8 a1 = *(const half8*)(xr2 + (kk + 1) * 32);
            ax  = __builtin_amdgcn_mfma_f32_16x16x32_f16(a0, bfrag[kk],     ax,  0, 0, 0);
            ax2 = __builtin_amdgcn_mfma_f32_16x16x32_f16(a1, bfrag[kk + 1], ax2, 0, 0, 0);
        }
        #pragma unroll
        for (int r = 0; r < 4; ++r) ax[r] += ax2[r];
        return ax;
    };

    stage(0, 0);
    stage(1, 1);
    __syncthreads();
    f32x4 acc_x = xmm(0);

    const int ridx_base = row * 4 + kq;
    const int widx = (wg >> 2) * 512 + (ej >> 1) * 128 + eb * 4 + (wg & 3);

    for (int t = 0; t < T_STEPS; ++t) {
        const u64* rb = hrec + (size_t)(t & 1) * RECS_PER_PARITY;
        const u32 target = (u32)(t + 1);

        u64 rec[64];
        unsigned spins = 0;
        for (;;) {
            #pragma unroll
            for (int kk = 0; kk < 16; ++kk) {
                #pragma unroll
                for (int s = 0; s < 4; ++s)
                    rec[kk * 4 + s] = AT_LD_U64(&rb[kk * 512 + s * 128 + ridx_base]);
            }
            int ok = 1;
            #pragma unroll
            for (int i = 0; i < 64; ++i)
                ok &= ((u32)(rec[i] >> 32) == target);
            if (__all(ok)) break;
            if (++spins > 300000u) break;
        }

        float* gb = &gbuf[(t & 1) * (BATCH * GSTRIDE)];
        {
            f32x4 acc  = acc_x;
            f32x4 acc2 = {0.f, 0.f, 0.f, 0.f};
            #pragma unroll
            for (int kk = 0; kk < 16; kk += 2) {
                union { u32 d[4]; half8 h; } a0, a1;
                #pragma unroll
                for (int s = 0; s < 4; ++s) {
                    a0.d[s] = (u32)rec[kk * 4 + s];
                    a1.d[s] = (u32)rec[(kk + 1) * 4 + s];
                }
                acc  = __builtin_amdgcn_mfma_f32_16x16x32_f16(a0.h, bfrag[16 + kk],     acc,  0, 0, 0);
                acc2 = __builtin_amdgcn_mfma_f32_16x16x32_f16(a1.h, bfrag[16 + kk + 1], acc2, 0, 0, 0);
            }
            #pragma unroll
            for (int r = 0; r < 4; ++r) {
                gb[(mt * 16 + kq * 4 + r) * GSTRIDE + nt * 16 + n_local] =
                    acc[r] + acc2[r];
            }
        }
        __syncthreads();

        float h_val;
        {
            float pi = gb[eb * GSTRIDE + ej]      + bi_v;
            float pf = gb[eb * GSTRIDE + 8 + ej]  + bf_v;
            float pg = gb[eb * GSTRIDE + 16 + ej] + bc_v;
            float po = gb[eb * GSTRIDE + 24 + ej] + bo_v;
            float ig = sigmoidf_(pi);
            float fg = sigmoidf_(pf);
            float gg = tanhf_(pg);
            float og = sigmoidf_(po);
            c_state  = fg * c_state + ig * gg;
            h_val    = og * tanhf_(c_state);

            if (t + 1 < T_STEPS) {
                _Float16 hh = (_Float16)h_val;
                u32 hu  = (u32)__builtin_bit_cast(unsigned short, hh);
                u32 oth = __shfl_down(hu, 1);
                if ((tid & 1) == 0) {
                    AT_ST_U64(&hrec[(size_t)((t + 1) & 1) * RECS_PER_PARITY + widx],
                              ((u64)(u32)(t + 2) << 32) | (u64)(hu | (oth << 16)));
                }
            }
        }

        out[((size_t)eb * T_STEPS + t) * H + ecol] = h_val;
        if (t + 1 < T_STEPS) {
            acc_x = xmm((t + 1) & 1);
            if (t + 2 < T_STEPS) stage(t + 2, t & 1);
        }
    }
}

// ======================= launcher ======================================
extern "C" void kernel_launch(void* const* d_in, const int* in_sizes, int n_in,
                              void* d_out, int out_size, void* d_ws, size_t ws_size,
                              hipStream_t stream) {
    const float* x           = (const float*)d_in[0];
    const float* init_states = (const float*)d_in[1];
    const float* Wi = (const float*)d_in[2];
    const float* Ui = (const float*)d_in[3];
    const float* bi = (const float*)d_in[4];
    const float* Wf = (const float*)d_in[5];
    const float* Uf = (const float*)d_in[6];
    const float* bf = (const float*)d_in[7];
    const float* Wc = (const float*)d_in[8];
    const float* Uc = (const float*)d_in[9];
    const float* bc = (const float*)d_in[10];
    const float* Wo = (const float*)d_in[11];
    const float* Uo = (const float*)d_in[12];
    const float* bo = (const float*)d_in[13];
    float* out = (float*)d_out;

    const size_t HREC_BYTES = (size_t)2 * RECS_PER_PARITY * 8;  // 128 KB
    const size_t CST_BYTES  = (size_t)BATCH * H * 4;            //  64 KB

    // largest chunk size whose preg buffer fits the workspace
    static const int cands[] = {1024, 512, 256, 128, 64, 32, 16};
    int tc = 0;
    size_t preg_bytes = 0;
    for (int i = 0; i < 7; ++i) {
        size_t pb = (size_t)cands[i] * 2048 * 32 * 4;   // [tc][4][512][32] f32
        if (ws_size >= pb + HREC_BYTES + CST_BYTES) { tc = cands[i]; preg_bytes = pb; break; }
    }

    if (tc > 0) {
        float* preg = (float*)d_ws;
        u64*   hrec = (u64*)((char*)d_ws + preg_bytes);
        float* cst  = (float*)((char*)d_ws + preg_bytes + HREC_BYTES);

        const int nchunks = T_STEPS / tc;
        for (int c = 0; c < nchunks; ++c) {
            lstm_pregate<<<dim3(256), dim3(512), 0, stream>>>(
                x, Wi, Wf, Wc, Wo, bi, bf, bc, bo, preg, c * tc, tc);
            lstm_recur<<<dim3(NWG), dim3(256), 0, stream>>>(
                init_states, Ui, Uf, Uc, Uo, preg, out, hrec, cst, c * tc, tc);
        }
    } else {
        u64* hrec = (u64*)d_ws;
        lstm_persistent_fb<<<dim3(NWG), dim3(256), 0, stream>>>(
            x, init_states, Wi, Ui, bi, Wf, Uf, bf, Wc, Uc, bc, Wo, Uo, bo,
            out, hrec);
    }
}

// Round 6
// 5150.460 us; speedup vs baseline: 1.1519x; 1.1519x over previous
//
#include <hip/hip_runtime.h>

// Two-phase persistent LSTM for MI355X.  B=32, T=1024, D_IN=512, H=512.
//
// R10 = R8 poll (branch-free full-reload; R9's partial-retry poll REGRESSED:
// VGPR 172->236, FETCH +80MB — guarded per-kk reloads serialize and bloat
// codegen) + BARRIER-FREE recurrence step.
//
//   Recur wave n-column remap: 16 cols = 4 gates x 4 h-cols
//     (gi = n_local>>2, col = nt*4 + (n_local&3)).  After the 16 MFMAs the
//     4 gate pre-activations of each (batch,col) sit in the 4 lanes of a
//     quad (lane stride 4); a 2-stage __shfl_xor(4)/__shfl_xor(8) butterfly
//     transposes acc[4] (batch rows) against the gate axis.  Each lane then
//     owns ONE (b,col): gates, c_state, h, publish — pure register
//     dataflow.  __syncthreads and the gbuf LDS tile are DELETED (recur
//     uses zero LDS).  Throttle proof survives per-wave: a wave publishes
//     E+1 only after its poll(E) loads returned (data dep), so any wave
//     passing poll(E+1) knows all E-records were consumed.
//
// Structure (unchanged from R8):
//   pregate(chunk): 256 WGs x 512 thr (8 waves REQUIRED: (mt,gsel) =
//     (wave&1, wave>>1)).  preg[lt][gate][hcol][b] = x_t @ W_g + b_g
//     (f32, MFMA C-layout, bias folded) — layout consumed unchanged.
//   recur(chunk): 64 WGs x 256 thr, self-validating 8B h-records
//     {epoch(hi32)|2xf16(lo32)}; polling load IS the data load (R5: sentinel
//     indirection regresses).  Global epochs, monotone across chunks;
//     c_state persists in ws.
//   Chunked over T to fit any ws_size; falls back to R4 if ws < 4.4 MB.

#define T_STEPS 1024
#define BATCH   32
#define DIN     512
#define H       512
#define NWG     64
#define HC      8
#define XSTRIDE 520        // f16 elems; 1040B row = bank offset 4 -> 2-way max (free)
#define GSTRIDE 34         // padded f32 row stride of LDS gate tile (fallback only)
#define RECS_PER_PARITY 8192   // 16 kk * 512   (R4 record format)

typedef _Float16 half8  __attribute__((ext_vector_type(8)));
typedef _Float16 half4v __attribute__((ext_vector_type(4)));
typedef float    f32x4  __attribute__((ext_vector_type(4)));
typedef unsigned long long u64;
typedef unsigned int       u32;

#define AT_LD_U64(p)   __hip_atomic_load((const u64*)(p), __ATOMIC_RELAXED, __HIP_MEMORY_SCOPE_AGENT)
#define AT_ST_U64(p,v) __hip_atomic_store((u64*)(p), (v), __ATOMIC_RELAXED, __HIP_MEMORY_SCOPE_AGENT)

__device__ __forceinline__ float sigmoidf_(float x) {
    return 1.0f / (1.0f + __expf(-x));
}
__device__ __forceinline__ float tanhf_(float x) {
    return 1.0f - 2.0f / (1.0f + __expf(2.0f * x));
}

// ======================= kernel 1: pre-gate GEMM ========================
// Grid: 256 WGs x 512 threads = 32 col-blocks (cb: 16 h-cols) x 8 t-ranges.
// Waves (8): mt = wave&1 (batch half), gsel = wave>>1 (gate 0..3) — one
// gate per wave.  Output preg[lt][gate][hcol][b], b fastest, bias folded,
// exactly MFMA C-layout so recur seeds its accumulator with one dwordx4.
__global__ __launch_bounds__(512, 1) void lstm_pregate(
    const float* __restrict__ x,
    const float* __restrict__ Wi, const float* __restrict__ Wf,
    const float* __restrict__ Wc, const float* __restrict__ Wo,
    const float* __restrict__ bi, const float* __restrict__ bf,
    const float* __restrict__ bc, const float* __restrict__ bo,
    float* __restrict__ preg, int t0, int tc)
{
    __shared__ _Float16 xbuf[2 * BATCH * XSTRIDE];   // ~65 KB, double-buffered

    const int tid  = threadIdx.x;
    const int wg   = blockIdx.x;
    const int cb   = wg & 31;          // h-cols [cb*16, cb*16+16)
    const int tq   = wg >> 5;          // t-range within chunk
    const int tcq  = tc >> 3;          // steps per t-range (>= 2)
    const int tb   = t0 + tq * tcq;    // global first step of this WG
    const int lane = tid & 63;
    const int wave = tid >> 6;         // 0..7
    const int mt   = wave & 1;         // batch half
    const int gsel = wave >> 1;        // gate 0..3  (8 waves REQUIRED)
    const int n_local = lane & 15;
    const int kq   = lane >> 4;
    const int row  = mt * 16 + n_local;    // batch row for A-frag
    const int hcol = cb * 16 + n_local;

    const float* Wmat = (gsel == 0) ? Wi : (gsel == 1) ? Wf : (gsel == 2) ? Wc : Wo;
    const float* bvec = (gsel == 0) ? bi : (gsel == 1) ? bf : (gsel == 2) ? bc : bo;
    const float bv = bvec[hcol];

    // ---- one-time: W B-fragments into VGPRs (one gate, 16 kk) ----------
    half8 bfrag[16];
    #pragma unroll
    for (int kk = 0; kk < 16; ++kk) {
        #pragma unroll
        for (int jj = 0; jj < 8; ++jj) {
            int k = kk * 32 + kq * 8 + jj;
            bfrag[kk][jj] = (_Float16)Wmat[k * H + hcol];
        }
    }

    // ---- x staging (f32 -> f16), 512-thread version --------------------
    // 32 rows x 16 threads/row; each thread 8 float4 loads (stride 64 cols).
    auto stage = [&](int t, int buf) {
        const int sb = tid >> 4;            // batch row 0..31
        const int so = (tid & 15) * 4;
        const float* xr = x + ((size_t)sb * T_STEPS + t) * DIN;
        _Float16* xb = &xbuf[buf * (BATCH * XSTRIDE)];
        #pragma unroll
        for (int q = 0; q < 8; ++q) {
            int colq = so + q * 64;
            float4 v = *(const float4*)(xr + colq);
            half4v hv = { (_Float16)v.x, (_Float16)v.y,
                          (_Float16)v.z, (_Float16)v.w };
            *(half4v*)&xb[sb * XSTRIDE + colq] = hv;
        }
    };

    stage(tb, 0);
    stage(tb + 1, 1);
    __syncthreads();

    for (int lt = 0; lt < tcq; ++lt) {
        f32x4 a0 = {0.f, 0.f, 0.f, 0.f};
        f32x4 a1 = {0.f, 0.f, 0.f, 0.f};
        const _Float16* xr2 =
            &xbuf[(lt & 1) * (BATCH * XSTRIDE) + row * XSTRIDE + kq * 8];
        #pragma unroll
        for (int kk = 0; kk < 16; kk += 2) {
            half8 v0 = *(const half8*)(xr2 + kk * 32);
            half8 v1 = *(const half8*)(xr2 + (kk + 1) * 32);
            a0 = __builtin_amdgcn_mfma_f32_16x16x32_f16(v0, bfrag[kk],     a0, 0, 0, 0);
            a1 = __builtin_amdgcn_mfma_f32_16x16x32_f16(v1, bfrag[kk + 1], a1, 0, 0, 0);
        }
        f32x4 aw;
        #pragma unroll
        for (int r = 0; r < 4; ++r) aw[r] = a0[r] + a1[r] + bv;

        // C/D layout: col = n_local (-> hcol), row = kq*4 + r (-> batch
        // within half mt).  Chunk-local step index.
        const size_t base =
            (((size_t)(tb - t0 + lt) * 4 + gsel) * 512 + hcol) * 32
            + mt * 16 + kq * 4;
        *(f32x4*)&preg[base] = aw;

        __syncthreads();
        if (lt + 2 < tcq) stage(tb + lt + 2, lt & 1);
    }
}

// ======================= kernel 2: recurrence ===========================
// Barrier-free, zero-LDS step.  Wave n-cols = 4 gates x 4 h-cols.
__global__ __launch_bounds__(256, 1) void lstm_recur(
    const float* __restrict__ init_states,
    const float* __restrict__ Ui, const float* __restrict__ Uf,
    const float* __restrict__ Uc, const float* __restrict__ Uo,
    const float* __restrict__ preg,   // [tc][4][512][32] f32, bias folded
    float* __restrict__ out,
    u64* __restrict__ hrec,           // 2 parities x 8192 records
    float* __restrict__ cst,          // [32][512] persistent c-state
    int t0, int tc)
{
    const int tid  = threadIdx.x;
    const int wg   = blockIdx.x;
    const int lane = tid & 63;
    const int wave = tid >> 6;
    const int mt   = wave & 1;
    const int nt   = wave >> 1;
    const int n_local = lane & 15;
    const int kq   = lane >> 4;
    const int row  = mt * 16 + n_local;    // A-frag batch row (poll identity)

    // ---- per-lane identities --------------------------------------------
    const int gi   = n_local >> 2;          // gate of this lane's n-column
    const int cl   = n_local & 3;           // col within quad
    const int ejl  = nt * 4 + cl;           // local h-col 0..7
    const int wcol = wg * HC + ejl;         // B-frag n-column == owned h-col
    // post-transpose: this lane owns (eb, ecol):
    const int eb   = mt * 16 + kq * 4 + gi; // batch row owned
    const int ecol = wcol;

    // c-state: from init on chunk 0, else from ws
    float c_state = (t0 == 0) ? init_states[BATCH * H + eb * H + ecol]
                              : cst[eb * H + ecol];

    // producer record index (pair {ecol, ecol+1} of batch eb)
    const int widx = (wg >> 2) * 512 + (ejl >> 1) * 128 + eb * 4 + (wg & 3);

    // publish h0 (epoch 1, parity 0) only on chunk 0
    if (t0 == 0) {
        _Float16 h0 = (_Float16)init_states[eb * H + ecol];
        u32 hu  = (u32)__builtin_bit_cast(unsigned short, h0);
        u32 oth = __shfl_down(hu, 1);
        if ((lane & 1) == 0)
            AT_ST_U64(&hrec[widx], ((u64)1u << 32) | (u64)(hu | (oth << 16)));
    }

    // ---- one-time: U B-fragments into VGPRs ----------------------------
    const float* Umat = (gi == 0) ? Ui : (gi == 1) ? Uf : (gi == 2) ? Uc : Uo;
    half8 bfrag[16];                    // 64 VGPRs/lane, persistent
    #pragma unroll
    for (int kk = 0; kk < 16; ++kk) {
        #pragma unroll
        for (int jj = 0; jj < 8; ++jj) {
            int k = kk * 32 + kq * 8 + jj;
            bfrag[kk][jj] = (_Float16)Umat[k * H + wcol];
        }
    }

    // pre-gate in MFMA C-layout: one dwordx4/lane/step, prefetched 1 ahead
    const size_t pgbase =
        ((size_t)gi * 512 + wcol) * 32 + mt * 16 + kq * 4;
    f32x4 pg = *(const f32x4*)&preg[pgbase];           // lt = 0

    const int ridx_base = row * 4 + kq;
    const bool q0 = (lane >> 2) & 1;    // gi bit 0
    const bool q1 = (lane >> 3) & 1;    // gi bit 1

    for (int lt = 0; lt < tc; ++lt) {
        const int gt = t0 + lt;                        // global step
        const u64* rb = hrec + (size_t)(gt & 1) * RECS_PER_PARITY;
        const u32 target = (u32)(gt + 1);

        // ---- poll (R8 verbatim: branch-free full reload) ----------------
        u64 rec[64];
        unsigned spins = 0;
        for (;;) {
            #pragma unroll
            for (int kk = 0; kk < 16; ++kk) {
                #pragma unroll
                for (int s = 0; s < 4; ++s)
                    rec[kk * 4 + s] = AT_LD_U64(&rb[kk * 512 + s * 128 + ridx_base]);
            }
            int ok = 1;
            #pragma unroll
            for (int i = 0; i < 64; ++i)
                ok &= ((u32)(rec[i] >> 32) == target);
            if (__all(ok)) break;
            if (++spins > 300000u) break;   // safety valve
        }

        // prefetch next step's pre-gate (consumed after next poll)
        f32x4 pgn = pg;
        if (lt + 1 < tc)
            pgn = *(const f32x4*)&preg[(size_t)(lt + 1) * 65536 + pgbase];

        // ---- h-half matmul; acc starts at pre-gate (x@W + b) -----------
        f32x4 acc  = pg;
        f32x4 acc2 = {0.f, 0.f, 0.f, 0.f};
        #pragma unroll
        for (int kk = 0; kk < 16; kk += 2) {
            union { u32 d[4]; half8 h; } a0, a1;
            #pragma unroll
            for (int s = 0; s < 4; ++s) {
                a0.d[s] = (u32)rec[kk * 4 + s];
                a1.d[s] = (u32)rec[(kk + 1) * 4 + s];
            }
            acc  = __builtin_amdgcn_mfma_f32_16x16x32_f16(a0.h, bfrag[kk],     acc,  0, 0, 0);
            acc2 = __builtin_amdgcn_mfma_f32_16x16x32_f16(a1.h, bfrag[kk + 1], acc2, 0, 0, 0);
        }
        float a0v = acc[0] + acc2[0];
        float a1v = acc[1] + acc2[1];
        float a2v = acc[2] + acc2[2];
        float a3v = acc[3] + acc2[3];

        // ---- in-wave 4x4 transpose across quad (gate axis <-> r axis) ---
        // stage 1 (lane xor 4 = gi bit 0):  a1[e] = (e0==q0) ? a[e] : partner a[e^1]
        float t0_ = __shfl_xor(a1v, 4);
        float t1_ = __shfl_xor(a0v, 4);
        float t2_ = __shfl_xor(a3v, 4);
        float t3_ = __shfl_xor(a2v, 4);
        float b0 = q0 ? t0_ : a0v;
        float b1 = q0 ? a1v : t1_;
        float b2 = q0 ? t2_ : a2v;
        float b3 = q0 ? a3v : t3_;
        // stage 2 (lane xor 8 = gi bit 1):  a2[e] = (e1==q1) ? b[e] : partner b[e^2]
        float u0 = __shfl_xor(b2, 8);
        float u1 = __shfl_xor(b3, 8);
        float u2 = __shfl_xor(b0, 8);
        float u3 = __shfl_xor(b1, 8);
        float pi  = q1 ? u0 : b0;
        float pf  = q1 ? u1 : b1;
        float pgg = q1 ? b2 : u2;
        float po  = q1 ? b3 : u3;

        // ---- gates + state update + immediate publish (no barrier) -----
        float ig = sigmoidf_(pi);
        float fg = sigmoidf_(pf);
        float gg = tanhf_(pgg);
        float og = sigmoidf_(po);
        c_state  = fg * c_state + ig * gg;
        float h_val = og * tanhf_(c_state);

        if (gt + 1 < T_STEPS) {
            _Float16 hh = (_Float16)h_val;
            u32 hu  = (u32)__builtin_bit_cast(unsigned short, hh);
            u32 oth = __shfl_down(hu, 1);
            if ((lane & 1) == 0) {
                AT_ST_U64(&hrec[(size_t)((gt + 1) & 1) * RECS_PER_PARITY + widx],
                          ((u64)(u32)(gt + 2) << 32) | (u64)(hu | (oth << 16)));
            }
        }

        // off-critical-path tail
        out[((size_t)eb * T_STEPS + gt) * H + ecol] = h_val;
        pg = pgn;
    }

    // persist c-state for the next chunk launch
    cst[eb * H + ecol] = c_state;
}

// ======================= fallback: R4 single kernel =====================
__global__ __launch_bounds__(256, 1) void lstm_persistent_fb(
    const float* __restrict__ x,
    const float* __restrict__ init_states,
    const float* __restrict__ Wi, const float* __restrict__ Ui, const float* __restrict__ bi,
    const float* __restrict__ Wf, const float* __restrict__ Uf, const float* __restrict__ bf,
    const float* __restrict__ Wc, const float* __restrict__ Uc, const float* __restrict__ bc,
    const float* __restrict__ Wo, const float* __restrict__ Uo, const float* __restrict__ bo,
    float* __restrict__ out,
    u64* __restrict__ hrec)
{
    __shared__ _Float16 xbuf[2 * BATCH * XSTRIDE];
    __shared__ float    gbuf[2 * BATCH * GSTRIDE];

    const int tid  = threadIdx.x;
    const int wg   = blockIdx.x;
    const int lane = tid & 63;
    const int wave = tid >> 6;
    const int mt   = wave & 1;
    const int nt   = wave >> 1;
    const int row  = mt * 16 + (lane & 15);
    const int kq   = lane >> 4;

    const int eb   = tid >> 3;
    const int ej   = tid & 7;
    const int ecol = wg * HC + ej;

    float c_state = init_states[BATCH * H + eb * H + ecol];
    {
        _Float16 h0 = (_Float16)init_states[eb * H + ecol];
        u32 hu  = (u32)__builtin_bit_cast(unsigned short, h0);
        u32 oth = __shfl_down(hu, 1);
        if ((tid & 1) == 0) {
            const int ridx = (wg >> 2) * 512 + (ej >> 1) * 128 + eb * 4 + (wg & 3);
            AT_ST_U64(&hrec[ridx], ((u64)1u << 32) | (u64)(hu | (oth << 16)));
        }
    }

    const int n_local = lane & 15;
    const int gi   = nt * 2 + (n_local >> 3);
    const int wcol = wg * HC + (n_local & 7);
    const float* Wmat = (gi == 0) ? Wi : (gi == 1) ? Wf : (gi == 2) ? Wc : Wo;
    const float* Umat = (gi == 0) ? Ui : (gi == 1) ? Uf : (gi == 2) ? Uc : Uo;

    half8 bfrag[32];
    #pragma unroll
    for (int kk = 0; kk < 16; ++kk) {
        #pragma unroll
        for (int jj = 0; jj < 8; ++jj) {
            int k = kk * 32 + kq * 8 + jj;
            bfrag[kk][jj]      = (_Float16)Wmat[k * H + wcol];
            bfrag[16 + kk][jj] = (_Float16)Umat[k * H + wcol];
        }
    }

    const float bi_v = bi[ecol], bf_v = bf[ecol], bc_v = bc[ecol], bo_v = bo[ecol];

    auto stage = [&](int t, int buf) {
        const int sb = tid >> 3;
        const int so = (tid & 7) * 4;
        const float* xr = x + ((size_t)sb * T_STEPS + t) * DIN;
        _Float16* xb = &xbuf[buf * (BATCH * XSTRIDE)];
        #pragma unroll
        for (int q = 0; q < 16; ++q) {
            int colq = so + q * 32;
            float4 v = *(const float4*)(xr + colq);
            half4v hv = { (_Float16)v.x, (_Float16)v.y,
                          (_Float16)v.z, (_Float16)v.w };
            *(half4v*)&xb[sb * XSTRIDE + colq] = hv;
        }
    };
    auto xmm = [&](int buf) -> f32x4 {
        f32x4 ax  = {0.f, 0.f, 0.f, 0.f};
        f32x4 ax2 = {0.f, 0.f, 0.f, 0.f};
        const _Float16* xr2 = &xbuf[buf * (BATCH * XSTRIDE) + row * XSTRIDE + kq * 8];
        #pragma unroll
        for (int kk = 0; kk < 16; kk += 2) {
            half8 a0 = *(const half8*)(xr2 + kk * 32);
            half8 a1 = *(const half8*)(xr2 + (kk + 1) * 32);
            ax  = __builtin_amdgcn_mfma_f32_16x16x32_f16(a0, bfrag[kk],     ax,  0, 0, 0);
            ax2 = __builtin_amdgcn_mfma_f32_16x16x32_f16(a1, bfrag[kk + 1], ax2, 0, 0, 0);
        }
        #pragma unroll
        for (int r = 0; r < 4; ++r) ax[r] += ax2[r];
        return ax;
    };

    stage(0, 0);
    stage(1, 1);
    __syncthreads();
    f32x4 acc_x = xmm(0);

    const int ridx_base = row * 4 + kq;
    const int widx = (wg >> 2) * 512 + (ej >> 1) * 128 + eb * 4 + (wg & 3);

    for (int t = 0; t < T_STEPS; ++t) {
        const u64* rb = hrec + (size_t)(t & 1) * RECS_PER_PARITY;
        const u32 target = (u32)(t + 1);

        u64 rec[64];
        unsigned spins = 0;
        for (;;) {
            #pragma unroll
            for (int kk = 0; kk < 16; ++kk) {
                #pragma unroll
                for (int s = 0; s < 4; ++s)
                    rec[kk * 4 + s] = AT_LD_U64(&rb[kk * 512 + s * 128 + ridx_base]);
            }
            int ok = 1;
            #pragma unroll
            for (int i = 0; i < 64; ++i)
                ok &= ((u32)(rec[i] >> 32) == target);
            if (__all(ok)) break;
            if (++spins > 300000u) break;
        }

        float* gb = &gbuf[(t & 1) * (BATCH * GSTRIDE)];
        {
            f32x4 acc  = acc_x;
            f32x4 acc2 = {0.f, 0.f, 0.f, 0.f};
            #pragma unroll
            for (int kk = 0; kk < 16; kk += 2) {
                union { u32 d[4]; half8 h; } a0, a1;
                #pragma unroll
                for (int s = 0; s < 4; ++s) {
                    a0.d[s] = (u32)rec[kk * 4 + s];
                    a1.d[s] = (u32)rec[(kk + 1) * 4 + s];
                }
                acc  = __builtin_amdgcn_mfma_f32_16x16x32_f16(a0.h, bfrag[16 + kk],     acc,  0, 0, 0);
                acc2 = __builtin_amdgcn_mfma_f32_16x16x32_f16(a1.h, bfrag[16 + kk + 1], acc2, 0, 0, 0);
            }
            #pragma unroll
            for (int r = 0; r < 4; ++r) {
                gb[(mt * 16 + kq * 4 + r) * GSTRIDE + nt * 16 + n_local] =
                    acc[r] + acc2[r];
            }
        }
        __syncthreads();

        float h_val;
        {
            float pi = gb[eb * GSTRIDE + ej]      + bi_v;
            float pf = gb[eb * GSTRIDE + 8 + ej]  + bf_v;
            float pg = gb[eb * GSTRIDE + 16 + ej] + bc_v;
            float po = gb[eb * GSTRIDE + 24 + ej] + bo_v;
            float ig = sigmoidf_(pi);
            float fg = sigmoidf_(pf);
            float gg = tanhf_(pg);
            float og = sigmoidf_(po);
            c_state  = fg * c_state + ig * gg;
            h_val    = og * tanhf_(c_state);

            if (t + 1 < T_STEPS) {
                _Float16 hh = (_Float16)h_val;
                u32 hu  = (u32)__builtin_bit_cast(unsigned short, hh);
                u32 oth = __shfl_down(hu, 1);
                if ((tid & 1) == 0) {
                    AT_ST_U64(&hrec[(size_t)((t + 1) & 1) * RECS_PER_PARITY + widx],
                              ((u64)(u32)(t + 2) << 32) | (u64)(hu | (oth << 16)));
                }
            }
        }

        out[((size_t)eb * T_STEPS + t) * H + ecol] = h_val;
        if (t + 1 < T_STEPS) {
            acc_x = xmm((t + 1) & 1);
            if (t + 2 < T_STEPS) stage(t + 2, t & 1);
        }
    }
}

// ======================= launcher ======================================
extern "C" void kernel_launch(void* const* d_in, const int* in_sizes, int n_in,
                              void* d_out, int out_size, void* d_ws, size_t ws_size,
                              hipStream_t stream) {
    const float* x           = (const float*)d_in[0];
    const float* init_states = (const float*)d_in[1];
    const float* Wi = (const float*)d_in[2];
    const float* Ui = (const float*)d_in[3];
    const float* bi = (const float*)d_in[4];
    const float* Wf = (const float*)d_in[5];
    const float* Uf = (const float*)d_in[6];
    const float* bf = (const float*)d_in[7];
    const float* Wc = (const float*)d_in[8];
    const float* Uc = (const float*)d_in[9];
    const float* bc = (const float*)d_in[10];
    const float* Wo = (const float*)d_in[11];
    const float* Uo = (const float*)d_in[12];
    const float* bo = (const float*)d_in[13];
    float* out = (float*)d_out;

    const size_t HREC_BYTES = (size_t)2 * RECS_PER_PARITY * 8;  // 128 KB
    const size_t CST_BYTES  = (size_t)BATCH * H * 4;            //  64 KB

    // largest chunk size whose preg buffer fits the workspace
    static const int cands[] = {1024, 512, 256, 128, 64, 32, 16};
    int tc = 0;
    size_t preg_bytes = 0;
    for (int i = 0; i < 7; ++i) {
        size_t pb = (size_t)cands[i] * 2048 * 32 * 4;   // [tc][4][512][32] f32
        if (ws_size >= pb + HREC_BYTES + CST_BYTES) { tc = cands[i]; preg_bytes = pb; break; }
    }

    if (tc > 0) {
        float* preg = (float*)d_ws;
        u64*   hrec = (u64*)((char*)d_ws + preg_bytes);
        float* cst  = (float*)((char*)d_ws + preg_bytes + HREC_BYTES);

        const int nchunks = T_STEPS / tc;
        for (int c = 0; c < nchunks; ++c) {
            lstm_pregate<<<dim3(256), dim3(512), 0, stream>>>(
                x, Wi, Wf, Wc, Wo, bi, bf, bc, bo, preg, c * tc, tc);
            lstm_recur<<<dim3(NWG), dim3(256), 0, stream>>>(
                init_states, Ui, Uf, Uc, Uo, preg, out, hrec, cst, c * tc, tc);
        }
    } else {
        u64* hrec = (u64*)d_ws;
        lstm_persistent_fb<<<dim3(NWG), dim3(256), 0, stream>>>(
            x, init_states, Wi, Ui, bi, Wf, Uf, bf, Wc, Uc, bc, Wo, Uo, bo,
            out, hrec);
    }
}

// Round 7
// 2990.057 us; speedup vs baseline: 1.9841x; 1.7225x over previous
//
#include <hip/hip_runtime.h>

// Two-phase persistent LSTM for MI355X.  B=32, T=1024, D_IN=512, H=512.
//
// R11 = split-poll recurrence.  Evidence chain:
//   R8  (full poll + barrier/gbuf):        2030 us/recur, poll FETCH ~87MB
//   R10 (full poll, barrier-free):         2356 us/recur, poll FETCH ~186MB
//   -> the barrier kept waves phase-aligned (fewer wasted attempts); the
//      step floor is (attempt burst RTT under LLC congestion) x attempts.
//      Grid attempt burst was 8 MB because nt=0/nt=1 waves of each (wg,mt)
//      pair poll IDENTICAL records.
// R11: each wave polls only its kk half (32 records, 16KB/wave -> 4 MB
// grid burst), pair exchanges payloads via parity-double-buffered LDS
// (64 KB) around ONE __syncthreads/step (also restores alignment).  After
// the exchange, R10's correctness-proven in-wave 4x4 transpose keeps gates
// in registers (no gbuf, no 2nd barrier).  Throttle proof: write(E+2) is
// after barrier(E+1) which is after every wave's LDS-read(E); parity banks
// separate write(E+1) from read(E).
//
// Structure otherwise unchanged (R8):
//   pregate(chunk): 256 WGs x 512 thr (8 waves REQUIRED: (mt,gsel) =
//     (wave&1, wave>>1)).  preg[lt][gate][hcol][b] = x_t @ W_g + b_g
//     (f32, MFMA C-layout, bias folded).
//   recur(chunk): 64 WGs x 256 thr, self-validating 8B h-records
//     {epoch(hi32)|2xf16(lo32)}; polling load IS the data load (R5:
//     sentinel indirection regresses; R9: partial-retry poll regresses).
//     Global epochs, monotone across chunks; c_state persists in ws.
//   Chunked over T to fit any ws_size; falls back to R4 if ws < 4.4 MB.

#define T_STEPS 1024
#define BATCH   32
#define DIN     512
#define H       512
#define NWG     64
#define HC      8
#define XSTRIDE 520        // f16 elems; 1040B row = bank offset 4 -> 2-way max (free)
#define GSTRIDE 34         // padded f32 row stride of LDS gate tile (fallback only)
#define RECS_PER_PARITY 8192   // 16 kk * 512   (R4 record format)

typedef _Float16 half8  __attribute__((ext_vector_type(8)));
typedef _Float16 half4v __attribute__((ext_vector_type(4)));
typedef float    f32x4  __attribute__((ext_vector_type(4)));
typedef unsigned int u32;
typedef unsigned long long u64;
typedef u32 u32x4 __attribute__((ext_vector_type(4)));

#define AT_LD_U64(p)   __hip_atomic_load((const u64*)(p), __ATOMIC_RELAXED, __HIP_MEMORY_SCOPE_AGENT)
#define AT_ST_U64(p,v) __hip_atomic_store((u64*)(p), (v), __ATOMIC_RELAXED, __HIP_MEMORY_SCOPE_AGENT)

__device__ __forceinline__ float sigmoidf_(float x) {
    return 1.0f / (1.0f + __expf(-x));
}
__device__ __forceinline__ float tanhf_(float x) {
    return 1.0f - 2.0f / (1.0f + __expf(2.0f * x));
}

// ======================= kernel 1: pre-gate GEMM ========================
// Grid: 256 WGs x 512 threads = 32 col-blocks (cb: 16 h-cols) x 8 t-ranges.
// Waves (8): mt = wave&1 (batch half), gsel = wave>>1 (gate 0..3) — one
// gate per wave.  Output preg[lt][gate][hcol][b], b fastest, bias folded,
// exactly MFMA C-layout so recur seeds its accumulator with one dwordx4.
__global__ __launch_bounds__(512, 1) void lstm_pregate(
    const float* __restrict__ x,
    const float* __restrict__ Wi, const float* __restrict__ Wf,
    const float* __restrict__ Wc, const float* __restrict__ Wo,
    const float* __restrict__ bi, const float* __restrict__ bf,
    const float* __restrict__ bc, const float* __restrict__ bo,
    float* __restrict__ preg, int t0, int tc)
{
    __shared__ _Float16 xbuf[2 * BATCH * XSTRIDE];   // ~65 KB, double-buffered

    const int tid  = threadIdx.x;
    const int wg   = blockIdx.x;
    const int cb   = wg & 31;          // h-cols [cb*16, cb*16+16)
    const int tq   = wg >> 5;          // t-range within chunk
    const int tcq  = tc >> 3;          // steps per t-range (>= 2)
    const int tb   = t0 + tq * tcq;    // global first step of this WG
    const int lane = tid & 63;
    const int wave = tid >> 6;         // 0..7
    const int mt   = wave & 1;         // batch half
    const int gsel = wave >> 1;        // gate 0..3  (8 waves REQUIRED)
    const int n_local = lane & 15;
    const int kq   = lane >> 4;
    const int row  = mt * 16 + n_local;    // batch row for A-frag
    const int hcol = cb * 16 + n_local;

    const float* Wmat = (gsel == 0) ? Wi : (gsel == 1) ? Wf : (gsel == 2) ? Wc : Wo;
    const float* bvec = (gsel == 0) ? bi : (gsel == 1) ? bf : (gsel == 2) ? bc : bo;
    const float bv = bvec[hcol];

    // ---- one-time: W B-fragments into VGPRs (one gate, 16 kk) ----------
    half8 bfrag[16];
    #pragma unroll
    for (int kk = 0; kk < 16; ++kk) {
        #pragma unroll
        for (int jj = 0; jj < 8; ++jj) {
            int k = kk * 32 + kq * 8 + jj;
            bfrag[kk][jj] = (_Float16)Wmat[k * H + hcol];
        }
    }

    // ---- x staging (f32 -> f16), 512-thread version --------------------
    // 32 rows x 16 threads/row; each thread 8 float4 loads (stride 64 cols).
    auto stage = [&](int t, int buf) {
        const int sb = tid >> 4;            // batch row 0..31
        const int so = (tid & 15) * 4;
        const float* xr = x + ((size_t)sb * T_STEPS + t) * DIN;
        _Float16* xb = &xbuf[buf * (BATCH * XSTRIDE)];
        #pragma unroll
        for (int q = 0; q < 8; ++q) {
            int colq = so + q * 64;
            float4 v = *(const float4*)(xr + colq);
            half4v hv = { (_Float16)v.x, (_Float16)v.y,
                          (_Float16)v.z, (_Float16)v.w };
            *(half4v*)&xb[sb * XSTRIDE + colq] = hv;
        }
    };

    stage(tb, 0);
    stage(tb + 1, 1);
    __syncthreads();

    for (int lt = 0; lt < tcq; ++lt) {
        f32x4 a0 = {0.f, 0.f, 0.f, 0.f};
        f32x4 a1 = {0.f, 0.f, 0.f, 0.f};
        const _Float16* xr2 =
            &xbuf[(lt & 1) * (BATCH * XSTRIDE) + row * XSTRIDE + kq * 8];
        #pragma unroll
        for (int kk = 0; kk < 16; kk += 2) {
            half8 v0 = *(const half8*)(xr2 + kk * 32);
            half8 v1 = *(const half8*)(xr2 + (kk + 1) * 32);
            a0 = __builtin_amdgcn_mfma_f32_16x16x32_f16(v0, bfrag[kk],     a0, 0, 0, 0);
            a1 = __builtin_amdgcn_mfma_f32_16x16x32_f16(v1, bfrag[kk + 1], a1, 0, 0, 0);
        }
        f32x4 aw;
        #pragma unroll
        for (int r = 0; r < 4; ++r) aw[r] = a0[r] + a1[r] + bv;

        // C/D layout: col = n_local (-> hcol), row = kq*4 + r (-> batch
        // within half mt).  Chunk-local step index.
        const size_t base =
            (((size_t)(tb - t0 + lt) * 4 + gsel) * 512 + hcol) * 32
            + mt * 16 + kq * 4;
        *(f32x4*)&preg[base] = aw;

        __syncthreads();
        if (lt + 2 < tcq) stage(tb + lt + 2, lt & 1);
    }
}

// ======================= kernel 2: recurrence ===========================
// Split-poll: wave (mt,nt) polls kk in [nt*8, nt*8+8); pair exchanges
// payloads via parity-double-buffered LDS around one barrier; in-wave
// transpose keeps gates in registers.
__global__ __launch_bounds__(256, 1) void lstm_recur(
    const float* __restrict__ init_states,
    const float* __restrict__ Ui, const float* __restrict__ Uf,
    const float* __restrict__ Uc, const float* __restrict__ Uo,
    const float* __restrict__ preg,   // [tc][4][512][32] f32, bias folded
    float* __restrict__ out,
    u64* __restrict__ hrec,           // 2 parities x 8192 records
    float* __restrict__ cst,          // [32][512] persistent c-state
    int t0, int tc)
{
    // [parity][mt][kk][lane][s] u32 payloads = 64 KB
    __shared__ u32 share[2][2][16][64][4];

    const int tid  = threadIdx.x;
    const int wg   = blockIdx.x;
    const int lane = tid & 63;
    const int wave = tid >> 6;
    const int mt   = wave & 1;
    const int nt   = wave >> 1;
    const int n_local = lane & 15;
    const int kq   = lane >> 4;
    const int row  = mt * 16 + n_local;    // A-frag batch row (poll identity)

    // ---- per-lane identities (R10 mapping: 16 n-cols = 4 gates x 4 cols) -
    const int gi   = n_local >> 2;          // gate of this lane's n-column
    const int cl   = n_local & 3;           // col within quad
    const int ejl  = nt * 4 + cl;           // local h-col 0..7
    const int wcol = wg * HC + ejl;         // B-frag n-column == owned h-col
    const int eb   = mt * 16 + kq * 4 + gi; // post-transpose owned batch row
    const int ecol = wcol;

    float c_state = (t0 == 0) ? init_states[BATCH * H + eb * H + ecol]
                              : cst[eb * H + ecol];

    const int widx = (wg >> 2) * 512 + (ejl >> 1) * 128 + eb * 4 + (wg & 3);

    if (t0 == 0) {
        _Float16 h0 = (_Float16)init_states[eb * H + ecol];
        u32 hu  = (u32)__builtin_bit_cast(unsigned short, h0);
        u32 oth = __shfl_down(hu, 1);
        if ((lane & 1) == 0)
            AT_ST_U64(&hrec[widx], ((u64)1u << 32) | (u64)(hu | (oth << 16)));
    }

    // ---- one-time: U B-fragments into VGPRs ----------------------------
    const float* Umat = (gi == 0) ? Ui : (gi == 1) ? Uf : (gi == 2) ? Uc : Uo;
    half8 bfrag[16];                    // 64 VGPRs/lane, persistent
    #pragma unroll
    for (int kk = 0; kk < 16; ++kk) {
        #pragma unroll
        for (int jj = 0; jj < 8; ++jj) {
            int k = kk * 32 + kq * 8 + jj;
            bfrag[kk][jj] = (_Float16)Umat[k * H + wcol];
        }
    }

    // pre-gate in MFMA C-layout: one dwordx4/lane/step, prefetched 1 ahead
    const size_t pgbase =
        ((size_t)gi * 512 + wcol) * 32 + mt * 16 + kq * 4;
    f32x4 pg = *(const f32x4*)&preg[pgbase];           // lt = 0

    const int ridx_base = row * 4 + kq;
    const int kk0 = nt * 8;             // own kk half
    const bool q0 = (lane >> 2) & 1;    // gi bit 0
    const bool q1 = (lane >> 3) & 1;    // gi bit 1

    for (int lt = 0; lt < tc; ++lt) {
        const int gt = t0 + lt;                        // global step
        const u64* rb = hrec + (size_t)(gt & 1) * RECS_PER_PARITY;
        const u32 target = (u32)(gt + 1);
        const int par = gt & 1;

        // ---- poll OWN 32 records (branch-free full reload) --------------
        u64 rec[32];
        unsigned spins = 0;
        for (;;) {
            #pragma unroll
            for (int kk2 = 0; kk2 < 8; ++kk2) {
                #pragma unroll
                for (int s = 0; s < 4; ++s)
                    rec[kk2 * 4 + s] =
                        AT_LD_U64(&rb[(kk0 + kk2) * 512 + s * 128 + ridx_base]);
            }
            int ok = 1;
            #pragma unroll
            for (int i = 0; i < 32; ++i)
                ok &= ((u32)(rec[i] >> 32) == target);
            if (__all(ok)) break;
            if (++spins > 300000u) break;   // safety valve
        }

        // ---- publish own payloads to LDS (parity bank gt&1) -------------
        #pragma unroll
        for (int kk2 = 0; kk2 < 8; ++kk2) {
            u32x4 v = { (u32)rec[kk2 * 4 + 0], (u32)rec[kk2 * 4 + 1],
                        (u32)rec[kk2 * 4 + 2], (u32)rec[kk2 * 4 + 3] };
            *(u32x4*)&share[par][mt][kk0 + kk2][lane][0] = v;
        }

        // prefetch next step's pre-gate (independent; overlaps barrier)
        f32x4 pgn = pg;
        if (lt + 1 < tc)
            pgn = *(const f32x4*)&preg[(size_t)(lt + 1) * 65536 + pgbase];

        __syncthreads();   // the ONLY barrier per step (exchange + throttle)

        // ---- read all 16 kk A-frag payloads from LDS --------------------
        u32x4 au[16];
        #pragma unroll
        for (int kk = 0; kk < 16; ++kk)
            au[kk] = *(const u32x4*)&share[par][mt][kk][lane][0];

        // ---- h-half matmul; acc starts at pre-gate (x@W + b) -----------
        f32x4 acc  = pg;
        f32x4 acc2 = {0.f, 0.f, 0.f, 0.f};
        #pragma unroll
        for (int kk = 0; kk < 16; kk += 2) {
            union { u32x4 v; half8 h; } a0, a1;
            a0.v = au[kk];
            a1.v = au[kk + 1];
            acc  = __builtin_amdgcn_mfma_f32_16x16x32_f16(a0.h, bfrag[kk],     acc,  0, 0, 0);
            acc2 = __builtin_amdgcn_mfma_f32_16x16x32_f16(a1.h, bfrag[kk + 1], acc2, 0, 0, 0);
        }
        float a0v = acc[0] + acc2[0];
        float a1v = acc[1] + acc2[1];
        float a2v = acc[2] + acc2[2];
        float a3v = acc[3] + acc2[3];

        // ---- in-wave 4x4 transpose across quad (gate axis <-> r axis) ---
        float t0_ = __shfl_xor(a1v, 4);
        float t1_ = __shfl_xor(a0v, 4);
        float t2_ = __shfl_xor(a3v, 4);
        float t3_ = __shfl_xor(a2v, 4);
        float b0 = q0 ? t0_ : a0v;
        float b1 = q0 ? a1v : t1_;
        float b2 = q0 ? t2_ : a2v;
        float b3 = q0 ? a3v : t3_;
        float u0 = __shfl_xor(b2, 8);
        float u1 = __shfl_xor(b3, 8);
        float u2 = __shfl_xor(b0, 8);
        float u3 = __shfl_xor(b1, 8);
        float pi  = q1 ? u0 : b0;
        float pf  = q1 ? u1 : b1;
        float pgg = q1 ? b2 : u2;
        float po  = q1 ? b3 : u3;

        // ---- gates + state update + immediate publish -------------------
        float ig = sigmoidf_(pi);
        float fg = sigmoidf_(pf);
        float gg = tanhf_(pgg);
        float og = sigmoidf_(po);
        c_state  = fg * c_state + ig * gg;
        float h_val = og * tanhf_(c_state);

        if (gt + 1 < T_STEPS) {
            _Float16 hh = (_Float16)h_val;
            u32 hu  = (u32)__builtin_bit_cast(unsigned short, hh);
            u32 oth = __shfl_down(hu, 1);
            if ((lane & 1) == 0) {
                AT_ST_U64(&hrec[(size_t)((gt + 1) & 1) * RECS_PER_PARITY + widx],
                          ((u64)(u32)(gt + 2) << 32) | (u64)(hu | (oth << 16)));
            }
        }

        // off-critical-path tail
        out[((size_t)eb * T_STEPS + gt) * H + ecol] = h_val;
        pg = pgn;
    }

    // persist c-state for the next chunk launch
    cst[eb * H + ecol] = c_state;
}

// ======================= fallback: R4 single kernel =====================
__global__ __launch_bounds__(256, 1) void lstm_persistent_fb(
    const float* __restrict__ x,
    const float* __restrict__ init_states,
    const float* __restrict__ Wi, const float* __restrict__ Ui, const float* __restrict__ bi,
    const float* __restrict__ Wf, const float* __restrict__ Uf, const float* __restrict__ bf,
    const float* __restrict__ Wc, const float* __restrict__ Uc, const float* __restrict__ bc,
    const float* __restrict__ Wo, const float* __restrict__ Uo, const float* __restrict__ bo,
    float* __restrict__ out,
    u64* __restrict__ hrec)
{
    __shared__ _Float16 xbuf[2 * BATCH * XSTRIDE];
    __shared__ float    gbuf[2 * BATCH * GSTRIDE];

    const int tid  = threadIdx.x;
    const int wg   = blockIdx.x;
    const int lane = tid & 63;
    const int wave = tid >> 6;
    const int mt   = wave & 1;
    const int nt   = wave >> 1;
    const int row  = mt * 16 + (lane & 15);
    const int kq   = lane >> 4;

    const int eb   = tid >> 3;
    const int ej   = tid & 7;
    const int ecol = wg * HC + ej;

    float c_state = init_states[BATCH * H + eb * H + ecol];
    {
        _Float16 h0 = (_Float16)init_states[eb * H + ecol];
        u32 hu  = (u32)__builtin_bit_cast(unsigned short, h0);
        u32 oth = __shfl_down(hu, 1);
        if ((tid & 1) == 0) {
            const int ridx = (wg >> 2) * 512 + (ej >> 1) * 128 + eb * 4 + (wg & 3);
            AT_ST_U64(&hrec[ridx], ((u64)1u << 32) | (u64)(hu | (oth << 16)));
        }
    }

    const int n_local = lane & 15;
    const int gi   = nt * 2 + (n_local >> 3);
    const int wcol = wg * HC + (n_local & 7);
    const float* Wmat = (gi == 0) ? Wi : (gi == 1) ? Wf : (gi == 2) ? Wc : Wo;
    const float* Umat = (gi == 0) ? Ui : (gi == 1) ? Uf : (gi == 2) ? Uc : Uo;

    half8 bfrag[32];
    #pragma unroll
    for (int kk = 0; kk < 16; ++kk) {
        #pragma unroll
        for (int jj = 0; jj < 8; ++jj) {
            int k = kk * 32 + kq * 8 + jj;
            bfrag[kk][jj]      = (_Float16)Wmat[k * H + wcol];
            bfrag[16 + kk][jj] = (_Float16)Umat[k * H + wcol];
        }
    }

    const float bi_v = bi[ecol], bf_v = bf[ecol], bc_v = bc[ecol], bo_v = bo[ecol];

    auto stage = [&](int t, int buf) {
        const int sb = tid >> 3;
        const int so = (tid & 7) * 4;
        const float* xr = x + ((size_t)sb * T_STEPS + t) * DIN;
        _Float16* xb = &xbuf[buf * (BATCH * XSTRIDE)];
        #pragma unroll
        for (int q = 0; q < 16; ++q) {
            int colq = so + q * 32;
            float4 v = *(const float4*)(xr + colq);
            half4v hv = { (_Float16)v.x, (_Float16)v.y,
                          (_Float16)v.z, (_Float16)v.w };
            *(half4v*)&xb[sb * XSTRIDE + colq] = hv;
        }
    };
    auto xmm = [&](int buf) -> f32x4 {
        f32x4 ax  = {0.f, 0.f, 0.f, 0.f};
        f32x4 ax2 = {0.f, 0.f, 0.f, 0.f};
        const _Float16* xr2 = &xbuf[buf * (BATCH * XSTRIDE) + row * XSTRIDE + kq * 8];
        #pragma unroll
        for (int kk = 0; kk < 16; kk += 2) {
            half8 a0 = *(const half8*)(xr2 + kk * 32);
            half8 a1 = *(const half8*)(xr2 + (kk + 1) * 32);
            ax  = __builtin_amdgcn_mfma_f32_16x16x32_f16(a0, bfrag[kk],     ax,  0, 0, 0);
            ax2 = __builtin_amdgcn_mfma_f32_16x16x32_f16(a1, bfrag[kk + 1], ax2, 0, 0, 0);
        }
        #pragma unroll
        for (int r = 0; r < 4; ++r) ax[r] += ax2[r];
        return ax;
    };

    stage(0, 0);
    stage(1, 1);
    __syncthreads();
    f32x4 acc_x = xmm(0);

    const int ridx_base = row * 4 + kq;
    const int widx = (wg >> 2) * 512 + (ej >> 1) * 128 + eb * 4 + (wg & 3);

    for (int t = 0; t < T_STEPS; ++t) {
        const u64* rb = hrec + (size_t)(t & 1) * RECS_PER_PARITY;
        const u32 target = (u32)(t + 1);

        u64 rec[64];
        unsigned spins = 0;
        for (;;) {
            #pragma unroll
            for (int kk = 0; kk < 16; ++kk) {
                #pragma unroll
                for (int s = 0; s < 4; ++s)
                    rec[kk * 4 + s] = AT_LD_U64(&rb[kk * 512 + s * 128 + ridx_base]);
            }
            int ok = 1;
            #pragma unroll
            for (int i = 0; i < 64; ++i)
                ok &= ((u32)(rec[i] >> 32) == target);
            if (__all(ok)) break;
            if (++spins > 300000u) break;
        }

        float* gb = &gbuf[(t & 1) * (BATCH * GSTRIDE)];
        {
            f32x4 acc  = acc_x;
            f32x4 acc2 = {0.f, 0.f, 0.f, 0.f};
            #pragma unroll
            for (int kk = 0; kk < 16; kk += 2) {
                union { u32 d[4]; half8 h; } a0, a1;
                #pragma unroll
                for (int s = 0; s < 4; ++s) {
                    a0.d[s] = (u32)rec[kk * 4 + s];
                    a1.d[s] = (u32)rec[(kk + 1) * 4 + s];
                }
                acc  = __builtin_amdgcn_mfma_f32_16x16x32_f16(a0.h, bfrag[16 + kk],     acc,  0, 0, 0);
                acc2 = __builtin_amdgcn_mfma_f32_16x16x32_f16(a1.h, bfrag[16 + kk + 1], acc2, 0, 0, 0);
            }
            #pragma unroll
            for (int r = 0; r < 4; ++r) {
                gb[(mt * 16 + kq * 4 + r) * GSTRIDE + nt * 16 + n_local] =
                    acc[r] + acc2[r];
            }
        }
        __syncthreads();

        float h_val;
        {
            float pi = gb[eb * GSTRIDE + ej]      + bi_v;
            float pf = gb[eb * GSTRIDE + 8 + ej]  + bf_v;
            float pg = gb[eb * GSTRIDE + 16 + ej] + bc_v;
            float po = gb[eb * GSTRIDE + 24 + ej] + bo_v;
            float ig = sigmoidf_(pi);
            float fg = sigmoidf_(pf);
            float gg = tanhf_(pg);
            float og = sigmoidf_(po);
            c_state  = fg * c_state + ig * gg;
            h_val    = og * tanhf_(c_state);

            if (t + 1 < T_STEPS) {
                _Float16 hh = (_Float16)h_val;
                u32 hu  = (u32)__builtin_bit_cast(unsigned short, hh);
                u32 oth = __shfl_down(hu, 1);
                if ((tid & 1) == 0) {
                    AT_ST_U64(&hrec[(size_t)((t + 1) & 1) * RECS_PER_PARITY + widx],
                              ((u64)(u32)(t + 2) << 32) | (u64)(hu | (oth << 16)));
                }
            }
        }

        out[((size_t)eb * T_STEPS + t) * H + ecol] = h_val;
        if (t + 1 < T_STEPS) {
            acc_x = xmm((t + 1) & 1);
            if (t + 2 < T_STEPS) stage(t + 2, t & 1);
        }
    }
}

// ======================= launcher ======================================
extern "C" void kernel_launch(void* const* d_in, const int* in_sizes, int n_in,
                              void* d_out, int out_size, void* d_ws, size_t ws_size,
                              hipStream_t stream) {
    const float* x           = (const float*)d_in[0];
    const float* init_states = (const float*)d_in[1];
    const float* Wi = (const float*)d_in[2];
    const float* Ui = (const float*)d_in[3];
    const float* bi = (const float*)d_in[4];
    const float* Wf = (const float*)d_in[5];
    const float* Uf = (const float*)d_in[6];
    const float* bf = (const float*)d_in[7];
    const float* Wc = (const float*)d_in[8];
    const float* Uc = (const float*)d_in[9];
    const float* bc = (const float*)d_in[10];
    const float* Wo = (const float*)d_in[11];
    const float* Uo = (const float*)d_in[12];
    const float* bo = (const float*)d_in[13];
    float* out = (float*)d_out;

    const size_t HREC_BYTES = (size_t)2 * RECS_PER_PARITY * 8;  // 128 KB
    const size_t CST_BYTES  = (size_t)BATCH * H * 4;            //  64 KB

    // largest chunk size whose preg buffer fits the workspace
    static const int cands[] = {1024, 512, 256, 128, 64, 32, 16};
    int tc = 0;
    size_t preg_bytes = 0;
    for (int i = 0; i < 7; ++i) {
        size_t pb = (size_t)cands[i] * 2048 * 32 * 4;   // [tc][4][512][32] f32
        if (ws_size >= pb + HREC_BYTES + CST_BYTES) { tc = cands[i]; preg_bytes = pb; break; }
    }

    if (tc > 0) {
        float* preg = (float*)d_ws;
        u64*   hrec = (u64*)((char*)d_ws + preg_bytes);
        float* cst  = (float*)((char*)d_ws + preg_bytes + HREC_BYTES);

        const int nchunks = T_STEPS / tc;
        for (int c = 0; c < nchunks; ++c) {
            lstm_pregate<<<dim3(256), dim3(512), 0, stream>>>(
                x, Wi, Wf, Wc, Wo, bi, bf, bc, bo, preg, c * tc, tc);
            lstm_recur<<<dim3(NWG), dim3(256), 0, stream>>>(
                init_states, Ui, Uf, Uc, Uo, preg, out, hrec, cst, c * tc, tc);
        }
    } else {
        u64* hrec = (u64*)d_ws;
        lstm_persistent_fb<<<dim3(NWG), dim3(256), 0, stream>>>(
            x, init_states, Wi, Ui, bi, Wf, Uf, bf, Wc, Uc, bc, Wo, Uo, bo,
            out, hrec);
    }
}